// Round 9
// baseline (519.726 us; speedup 1.0000x reference)
//
#include <hip/hip_runtime.h>

#define CAP 64
#define DD 48

typedef short v8s __attribute__((ext_vector_type(8)));
typedef float v4f __attribute__((ext_vector_type(4)));
typedef float v2f __attribute__((ext_vector_type(2)));

__device__ __forceinline__ unsigned int bf16r(float f) {   // round-to-nearest-even bf16
    unsigned int u = __float_as_uint(f);
    return (u + 0x7FFFu + ((u >> 16) & 1u)) >> 16;
}

__device__ __forceinline__ v8s ld_frag(const ushort* p) {  // p 8B-aligned in LDS
    const uint2* q = reinterpret_cast<const uint2*>(p);
    uint2 a = q[0], b = q[1];
    union { unsigned int u[4]; v8s v; } t;
    t.u[0] = a.x; t.u[1] = a.y; t.u[2] = b.x; t.u[3] = b.y;
    return t.v;
}

// ---------------- adjacency build (dst-bucketed, fixed capacity) ----------------
__global__ void build_adj_kernel(const int* __restrict__ ei, int E, int N,
                                 int* __restrict__ cnt, int* __restrict__ adj) {
    int e = blockIdx.x * blockDim.x + threadIdx.x;
    int Et = E + N;
    if (e >= Et) return;
    int s, d;
    if (e < E) { s = ei[e]; d = ei[E + e]; } else { s = e - E; d = e - E; }
    int pos = atomicAdd(&cnt[d], 1);
    if (pos < CAP) adj[d * CAP + pos] = s;
}

// ---------------- fp32 -> bf16 casts ----------------
__global__ void cast_x_kernel(const float* __restrict__ x, unsigned int* __restrict__ xb, long n2) {
    long i = (long)blockIdx.x * blockDim.x + threadIdx.x;
    if (i >= n2) return;
    float2 v = reinterpret_cast<const float2*>(x)[i];
    xb[i] = bf16r(v.x) | (bf16r(v.y) << 16);
}

// W [K][NC] fp32 -> WT [NC][K] bf16 (transposed: B-frag wants contiguous k per column)
__global__ void convw_kernel(const float* __restrict__ W, ushort* __restrict__ WT, int K, int NC) {
    int i = blockIdx.x * blockDim.x + threadIdx.x;
    if (i >= K * NC) return;
    int k = i / NC, n = i % NC;
    WT[n * K + k] = (ushort)bf16r(W[i]);
}

// ---------------- bf16 MFMA GEMM + fused attention dots ----------------
template<int K, int NCT, int HEADS>
__global__ void gemm_mfma(const ushort* __restrict__ Xb, const ushort* __restrict__ WT,
                          const float* __restrict__ att_s, const float* __restrict__ att_d,
                          ushort* __restrict__ Hb, float* __restrict__ asrc,
                          float* __restrict__ adst, int N) {
    __shared__ ushort XT_l[128 * 40];
    __shared__ ushort WT_l[96 * 40];
    int tid = threadIdx.x;
    int wv = tid >> 6, lane = tid & 63;
    int m = lane & 15, quad = lane >> 4;
    int rb = blockIdx.x * 128;
    int c0 = blockIdx.y * 96;
    int mw = wv * 32;
    v4f acc[2][6];
#pragma unroll
    for (int mi = 0; mi < 2; mi++)
#pragma unroll
        for (int nb = 0; nb < 6; nb++) acc[mi][nb] = (v4f){0.f, 0.f, 0.f, 0.f};

    for (int k0 = 0; k0 < K; k0 += 32) {
#pragma unroll
        for (int t = 0; t < 2; t++) {
            int ch = tid + t * 256;
            int r = ch >> 2, kq = ch & 3;
            int rg = rb + r;
            uint4 v = make_uint4(0u, 0u, 0u, 0u);
            if (rg < N) v = *reinterpret_cast<const uint4*>(&Xb[(long)rg * K + k0 + kq * 8]);
            uint2* d = reinterpret_cast<uint2*>(&XT_l[r * 40 + kq * 8]);
            d[0] = make_uint2(v.x, v.y);
            d[1] = make_uint2(v.z, v.w);
        }
#pragma unroll
        for (int t = 0; t < 2; t++) {
            int ch = tid + t * 256;
            if (ch < 384) {
                int wr = ch >> 2, kq = ch & 3;
                uint4 v = *reinterpret_cast<const uint4*>(&WT[(long)(c0 + wr) * K + k0 + kq * 8]);
                uint2* d = reinterpret_cast<uint2*>(&WT_l[wr * 40 + kq * 8]);
                d[0] = make_uint2(v.x, v.y);
                d[1] = make_uint2(v.z, v.w);
            }
        }
        __syncthreads();
        v8s af[2], bf[6];
        af[0] = ld_frag(&XT_l[(mw + m) * 40 + quad * 8]);
        af[1] = ld_frag(&XT_l[(mw + 16 + m) * 40 + quad * 8]);
#pragma unroll
        for (int nb = 0; nb < 6; nb++)
            bf[nb] = ld_frag(&WT_l[(nb * 16 + m) * 40 + quad * 8]);
#pragma unroll
        for (int mi = 0; mi < 2; mi++)
#pragma unroll
            for (int nb = 0; nb < 6; nb++)
                acc[mi][nb] = __builtin_amdgcn_mfma_f32_16x16x32_bf16(af[mi], bf[nb], acc[mi][nb], 0, 0, 0);
        __syncthreads();
    }

#pragma unroll
    for (int mi = 0; mi < 2; mi++)
#pragma unroll
        for (int r = 0; r < 4; r++) {
            int R = rb + mw + mi * 16 + quad * 4 + r;
            if (R < N) {
#pragma unroll
                for (int nb = 0; nb < 6; nb++)
                    Hb[(long)R * NCT + c0 + nb * 16 + m] = (ushort)bf16r(acc[mi][nb][r]);
            }
        }

    // ---- fused attention dots from fp32 accumulator ----
    float aS[6], aD[6];
    int h0 = c0 / DD;
#pragma unroll
    for (int nb = 0; nb < 6; nb++) {
        int cb = nb * 16 + m;
        int hl = cb / DD;
        int cih = cb - hl * DD;
        aS[nb] = att_s[(h0 + hl) * DD + cih];
        aD[nb] = att_d[(h0 + hl) * DD + cih];
    }
#pragma unroll
    for (int mi = 0; mi < 2; mi++)
#pragma unroll
        for (int r = 0; r < 4; r++) {
            float ps0 = 0.f, ps1 = 0.f, pd0 = 0.f, pd1 = 0.f;
#pragma unroll
            for (int nb = 0; nb < 3; nb++) {
                ps0 = fmaf(acc[mi][nb][r], aS[nb], ps0);
                pd0 = fmaf(acc[mi][nb][r], aD[nb], pd0);
            }
#pragma unroll
            for (int nb = 3; nb < 6; nb++) {
                ps1 = fmaf(acc[mi][nb][r], aS[nb], ps1);
                pd1 = fmaf(acc[mi][nb][r], aD[nb], pd1);
            }
#pragma unroll
            for (int d = 1; d < 16; d <<= 1) {
                ps0 += __shfl_xor(ps0, d); ps1 += __shfl_xor(ps1, d);
                pd0 += __shfl_xor(pd0, d); pd1 += __shfl_xor(pd1, d);
            }
            int R = rb + mw + mi * 16 + quad * 4 + r;
            if (m == 0 && R < N) {
                asrc[R * HEADS + h0]     = ps0;
                asrc[R * HEADS + h0 + 1] = ps1;
                adst[R * HEADS + h0]     = pd0;
                adst[R * HEADS + h0 + 1] = pd1;
            }
        }
}

// ---------------- dst-centric fused softmax + aggregate + bias + relu ----------------
// R9: channel-slice blocked gather. All waves traverse edges slice-by-slice
// (32 channels = N*64 B = 6.4 MB working set per slice, ~L2-resident) instead of
// full rows (38.4 MB, ~10% L2 hit). Lane = (edge-sub 0-3, ch-pair 0-15); per
// 16-edge chunk the edge indices + all-head weights are hoisted to registers;
// cross-edge reduction via shfl_xor 16/32 at the end.
template<int OUT, int HEADS, bool OBF16>
__global__ void agg_kernel(const unsigned int* __restrict__ Hb,
                           const float* __restrict__ asrc, const float* __restrict__ adst,
                           const int* __restrict__ adj, const int* __restrict__ cnt,
                           const float* __restrict__ bias,
                           unsigned int* __restrict__ Ob, float* __restrict__ Of, int N) {
    constexpr int SLICES = OUT / 32;
    constexpr int ROWU = OUT / 2;              // uints per row
    __shared__ float wlds[4][HEADS][CAP + 1];  // head stride 65 -> distinct banks
    __shared__ float dlds[4][HEADS];
    __shared__ int   slds[4][CAP];
    int wv = threadIdx.x >> 6;
    int lane = threadIdx.x & 63;
    int esub = lane >> 4;                      // edge subgroup 0..3
    int lp   = lane & 15;                      // ch-pair within slice
    int n = blockIdx.x * 4 + wv;
    bool valid = (n < N);
    int nn = valid ? n : 0;
    int deg_raw = cnt[nn];                     // issue cnt+adj concurrently
    int araw = adj[nn * CAP + lane];
    int deg = min(deg_raw, CAP);
    int s = (lane < deg) ? araw : 0;
    slds[wv][lane] = s;

    float av[HEADS], dvv[HEADS];
    if constexpr (HEADS == 4) {
        float4 t = *reinterpret_cast<const float4*>(&asrc[s * 4]);
        av[0] = t.x; av[1] = t.y; av[2] = t.z; av[3] = t.w;
        float4 u = *reinterpret_cast<const float4*>(&adst[nn * 4]);
        dvv[0] = u.x; dvv[1] = u.y; dvv[2] = u.z; dvv[3] = u.w;
    } else {
        float2 t = *reinterpret_cast<const float2*>(&asrc[s * 2]);
        av[0] = t.x; av[1] = t.y;
        float2 u = *reinterpret_cast<const float2*>(&adst[nn * 2]);
        dvv[0] = u.x; dvv[1] = u.y;
    }
    float w[HEADS];
#pragma unroll
    for (int h = 0; h < HEADS; h++) {
        float e = av[h] + dvv[h];
        e = (e < 0.f) ? 0.2f * e : e;               // leaky_relu, slope 0.2
        w[h] = (lane < deg) ? __expf(e) : 0.f;      // max-shift dropped: scale-invariant
        wlds[wv][h][lane] = w[h];
    }
#pragma unroll
    for (int h = 0; h < HEADS; h++) {               // den = wave-sum of weights
        float dsum = w[h];
#pragma unroll
        for (int off = 1; off < 64; off <<= 1) dsum += __shfl_xor(dsum, off);
        if (lane == 0) dlds[wv][h] = dsum;
    }
    __syncthreads();

    v2f acc2[SLICES];
#pragma unroll
    for (int sl = 0; sl < SLICES; sl++) acc2[sl] = (v2f){0.f, 0.f};

    for (int base = 0; base < deg; base += 16) {    // 16-edge chunks (pads: w=0, row 0)
        int se[4];
        float we[HEADS][4];
#pragma unroll
        for (int g = 0; g < 4; g++) {
            int e = base + (g << 2) + esub;
            se[g] = slds[wv][e];
#pragma unroll
            for (int h = 0; h < HEADS; h++) we[h][g] = wlds[wv][h][e];
        }
#pragma unroll
        for (int sl = 0; sl < SLICES; sl++) {
            unsigned int hv[4];
#pragma unroll
            for (int g = 0; g < 4; g++)
                hv[g] = Hb[se[g] * ROWU + sl * 16 + lp];
            constexpr int hA0 = 0;  (void)hA0;
#pragma unroll
            for (int g = 0; g < 4; g++) {
                int hA = (sl * 32) / DD;                 // folds per unrolled sl
                int hB = (sl * 32 + 30) / DD;
                float ww;
                if (hA == hB) ww = we[hA][g];
                else {
                    int cut = (hB * DD - sl * 32) >> 1;
                    ww = (lp < cut) ? we[hA][g] : we[hB][g];
                }
                v2f h2;
                h2.x = __uint_as_float(hv[g] << 16);
                h2.y = __uint_as_float(hv[g] & 0xFFFF0000u);
                acc2[sl] += ww * h2;                     // v_pk_fma_f32
            }
        }
    }

    // reduce across the 4 edge subgroups; esub 0 writes
#pragma unroll
    for (int sl = 0; sl < SLICES; sl++) {
        float ax = acc2[sl].x, ay = acc2[sl].y;
        ax += __shfl_xor(ax, 16); ay += __shfl_xor(ay, 16);
        ax += __shfl_xor(ax, 32); ay += __shfl_xor(ay, 32);
        if (valid && esub == 0) {
            int hA = (sl * 32) / DD;
            int hB = (sl * 32 + 30) / DD;
            float den;
            if (hA == hB) den = dlds[wv][hA];
            else {
                int cut = (hB * DD - sl * 32) >> 1;
                den = (lp < cut) ? dlds[wv][hA] : dlds[wv][hB];
            }
            float invd = 1.f / (den + 1e-16f);
            int ch = sl * 32 + lp * 2;
            float o0 = fmaxf(fmaf(ax, invd, bias[ch]), 0.f);
            float o1 = fmaxf(fmaf(ay, invd, bias[ch + 1]), 0.f);
            if (OBF16)
                Ob[((long)n * OUT + ch) >> 1] = bf16r(o0) | (bf16r(o1) << 16);
            else
                *reinterpret_cast<float2*>(&Of[(long)n * OUT + ch]) = make_float2(o0, o1);
        }
    }
}

// ---------------- mean-pool: 128-thread groups, 64-node chunks, 4x-unrolled ----------------
__global__ void pool_kernel(const float* __restrict__ O, const int* __restrict__ batch,
                            float* __restrict__ sums, float* __restrict__ counts, int N) {
    int grp = threadIdx.x >> 7;                 // 4 groups of 128 per block
    int c = threadIdx.x & 127;                  // channel lane; active if < 96
    int n0 = (blockIdx.x * 4 + grp) * 64;
    if (n0 >= N) return;
    int nend = min(N, n0 + 64);
    bool act = (c < 96);
    float acc = 0.f; int cl = 0;
    int cur = batch[n0];
    int n = n0;
    for (; n + 4 <= nend; n += 4) {
        int g0 = batch[n], g1 = batch[n + 1], g2 = batch[n + 2], g3 = batch[n + 3];
        float v0 = 0.f, v1 = 0.f, v2 = 0.f, v3 = 0.f;
        if (act) {
            v0 = O[(long)n * 96 + c];       v1 = O[(long)(n + 1) * 96 + c];
            v2 = O[(long)(n + 2) * 96 + c]; v3 = O[(long)(n + 3) * 96 + c];
        }
#define POOL_STEP(g, v)                                                        \
        if ((g) != cur) {                                                      \
            if (act) atomicAdd(&sums[cur * 96 + c], acc);                      \
            if (c == 96) atomicAdd(&counts[cur], (float)cl);                   \
            acc = 0.f; cl = 0; cur = (g);                                      \
        }                                                                      \
        acc += (v); cl++;
        POOL_STEP(g0, v0) POOL_STEP(g1, v1) POOL_STEP(g2, v2) POOL_STEP(g3, v3)
    }
    for (; n < nend; n++) {
        int g = batch[n];
        float v = act ? O[(long)n * 96 + c] : 0.f;
        POOL_STEP(g, v)
    }
#undef POOL_STEP
    if (act) atomicAdd(&sums[cur * 96 + c], acc);
    if (c == 96) atomicAdd(&counts[cur], (float)cl);
}

// ---------------- FC head: one block per graph ----------------
__global__ void fc_kernel(const float* __restrict__ sums, const float* __restrict__ counts,
                          const float* __restrict__ W1, const float* __restrict__ b1,
                          const float* __restrict__ W2, const float* __restrict__ b2,
                          float* __restrict__ out) {
    __shared__ float p[96];
    __shared__ float h1[192];
    int g = blockIdx.x, tid = threadIdx.x;     // 192 threads
    if (tid < 96) p[tid] = sums[g * 96 + tid] / fmaxf(counts[g], 1.0f);
    __syncthreads();
    float s = b1[tid];
    for (int c = 0; c < 96; c++) s = fmaf(p[c], W1[c * 192 + tid], s);
    h1[tid] = fmaxf(s, 0.f);
    __syncthreads();
    if (tid < 96) {
        float s2 = b2[tid];
        for (int j = 0; j < 192; j++) s2 = fmaf(h1[j], W2[j * 96 + tid], s2);
        out[g * 96 + tid] = s2;
    }
}

extern "C" void kernel_launch(void* const* d_in, const int* in_sizes, int n_in,
                              void* d_out, int out_size, void* d_ws, size_t ws_size,
                              hipStream_t stream) {
    const float* x     = (const float*)d_in[0];
    const int*   ei    = (const int*)d_in[1];
    const int*   batch = (const int*)d_in[2];
    const float* W0  = (const float*)d_in[3];
    const float* as0 = (const float*)d_in[4];
    const float* ad0 = (const float*)d_in[5];
    const float* b0  = (const float*)d_in[6];
    const float* W1  = (const float*)d_in[7];
    const float* as1 = (const float*)d_in[8];
    const float* ad1 = (const float*)d_in[9];
    const float* b1  = (const float*)d_in[10];
    const float* W2  = (const float*)d_in[11];
    const float* as2 = (const float*)d_in[12];
    const float* ad2 = (const float*)d_in[13];
    const float* b2  = (const float*)d_in[14];
    const float* fcW1 = (const float*)d_in[15];
    const float* fcb1 = (const float*)d_in[16];
    const float* fcW2 = (const float*)d_in[17];
    const float* fcb2 = (const float*)d_in[18];

    const int N = in_sizes[0] / 128;
    const int E = in_sizes[1] / 2;

    char* ws = (char*)d_ws;
    unsigned int* Xb   = (unsigned int*)ws;                          // N*128 bf16 = N*256 B
    unsigned int* Hb   = (unsigned int*)(ws + (size_t)N * 256);      // N*192 bf16 = N*384 B
    unsigned int* Ob   = (unsigned int*)(ws + (size_t)N * 640);      // N*192 bf16 = N*384 B
    float*        Obuf = (float*)(ws + (size_t)N * 1024);            // N*96 f32  = N*384 B
    float*        ASRC = (float*)(ws + (size_t)N * 1408);            // N*4 f
    float*        ADST = (float*)(ws + (size_t)N * 1424);            // N*4 f
    int*          ADJ  = (int*)(ws + (size_t)N * 1440);              // N*CAP i  = N*256 B
    int*          CNT  = (int*)(ws + (size_t)N * 1696);              // N i
    float*        SUMS = (float*)(ws + (size_t)N * 1700);            // 64*96 f
    float*        COUNTS = SUMS + 64 * 96;                           // 64 f
    ushort*       WT0  = (ushort*)(COUNTS + 64);                     // 192*128 bf16
    ushort*       WT1  = WT0 + 192 * 128;                            // 96*192 bf16
    ushort*       WT2  = WT1 + 96 * 192;                             // 96*96 bf16

    hipMemsetAsync(CNT, 0, (size_t)N * 4 + (64 * 96 + 64) * 4, stream);

    int Et = E + N;
    build_adj_kernel<<<(Et + 255) / 256, 256, 0, stream>>>(ei, E, N, CNT, ADJ);

    long n2 = (long)N * 64;
    cast_x_kernel<<<(int)((n2 + 255) / 256), 256, 0, stream>>>(x, Xb, n2);
    convw_kernel<<<(128 * 192 + 255) / 256, 256, 0, stream>>>(W0, WT0, 128, 192);
    convw_kernel<<<(192 * 96 + 255) / 256, 256, 0, stream>>>(W1, WT1, 192, 96);
    convw_kernel<<<(96 * 96 + 255) / 256, 256, 0, stream>>>(W2, WT2, 96, 96);

    int gb = (N + 127) / 128;

    // layer 0: 128 -> 4x48
    gemm_mfma<128, 192, 4><<<dim3(gb, 2), 256, 0, stream>>>((const ushort*)Xb, WT0, as0, ad0,
                                                            (ushort*)Hb, ASRC, ADST, N);
    agg_kernel<192, 4, true><<<(N + 3) / 4, 256, 0, stream>>>(Hb, ASRC, ADST, ADJ, CNT, b0, Ob, nullptr, N);

    // layer 1: 192 -> 2x48
    gemm_mfma<192, 96, 2><<<dim3(gb, 1), 256, 0, stream>>>((const ushort*)Ob, WT1, as1, ad1,
                                                           (ushort*)Hb, ASRC, ADST, N);
    agg_kernel<96, 2, true><<<(N + 3) / 4, 256, 0, stream>>>(Hb, ASRC, ADST, ADJ, CNT, b1, Ob, nullptr, N);

    // layer 2: 96 -> 2x48
    gemm_mfma<96, 96, 2><<<dim3(gb, 1), 256, 0, stream>>>((const ushort*)Ob, WT2, as2, ad2,
                                                          (ushort*)Hb, ASRC, ADST, N);
    agg_kernel<96, 2, false><<<(N + 3) / 4, 256, 0, stream>>>(Hb, ASRC, ADST, ADJ, CNT, b2, nullptr, Obuf, N);

    // pooling + FC head
    pool_kernel<<<(N / 256) + 1, 512, 0, stream>>>(Obuf, batch, SUMS, COUNTS, N);
    fc_kernel<<<64, 192, 0, stream>>>(SUMS, COUNTS, fcW1, fcb1, fcW2, fcb2, (float*)d_out);
}

// Round 10
// 480.418 us; speedup vs baseline: 1.0818x; 1.0818x over previous
//
#include <hip/hip_runtime.h>

#define CAP 64
#define DD 48

typedef short v8s __attribute__((ext_vector_type(8)));
typedef float v4f __attribute__((ext_vector_type(4)));
typedef float v2f __attribute__((ext_vector_type(2)));

__device__ __forceinline__ unsigned int bf16r(float f) {   // round-to-nearest-even bf16
    unsigned int u = __float_as_uint(f);
    return (u + 0x7FFFu + ((u >> 16) & 1u)) >> 16;
}

__device__ __forceinline__ v8s ld_frag(const ushort* p) {  // p 8B-aligned in LDS
    const uint2* q = reinterpret_cast<const uint2*>(p);
    uint2 a = q[0], b = q[1];
    union { unsigned int u[4]; v8s v; } t;
    t.u[0] = a.x; t.u[1] = a.y; t.u[2] = b.x; t.u[3] = b.y;
    return t.v;
}

// ---------------- adjacency build (dst-bucketed, fixed capacity) ----------------
__global__ void build_adj_kernel(const int* __restrict__ ei, int E, int N,
                                 int* __restrict__ cnt, int* __restrict__ adj) {
    int e = blockIdx.x * blockDim.x + threadIdx.x;
    int Et = E + N;
    if (e >= Et) return;
    int s, d;
    if (e < E) { s = ei[e]; d = ei[E + e]; } else { s = e - E; d = e - E; }
    int pos = atomicAdd(&cnt[d], 1);
    if (pos < CAP) adj[d * CAP + pos] = s;
}

// ---------------- fp32 -> bf16 casts ----------------
__global__ void cast_x_kernel(const float* __restrict__ x, unsigned int* __restrict__ xb, long n2) {
    long i = (long)blockIdx.x * blockDim.x + threadIdx.x;
    if (i >= n2) return;
    float2 v = reinterpret_cast<const float2*>(x)[i];
    xb[i] = bf16r(v.x) | (bf16r(v.y) << 16);
}

// W [K][NC] fp32 -> WT [NC][K] bf16 (transposed: B-frag wants contiguous k per column)
__global__ void convw_kernel(const float* __restrict__ W, ushort* __restrict__ WT, int K, int NC) {
    int i = blockIdx.x * blockDim.x + threadIdx.x;
    if (i >= K * NC) return;
    int k = i / NC, n = i % NC;
    WT[n * K + k] = (ushort)bf16r(W[i]);
}

// ---------------- bf16 MFMA GEMM + fused attention dots ----------------
template<int K, int NCT, int HEADS>
__global__ void gemm_mfma(const ushort* __restrict__ Xb, const ushort* __restrict__ WT,
                          const float* __restrict__ att_s, const float* __restrict__ att_d,
                          ushort* __restrict__ Hb, float* __restrict__ asrc,
                          float* __restrict__ adst, int N) {
    __shared__ ushort XT_l[128 * 40];
    __shared__ ushort WT_l[96 * 40];
    int tid = threadIdx.x;
    int wv = tid >> 6, lane = tid & 63;
    int m = lane & 15, quad = lane >> 4;
    int rb = blockIdx.x * 128;
    int c0 = blockIdx.y * 96;
    int mw = wv * 32;
    v4f acc[2][6];
#pragma unroll
    for (int mi = 0; mi < 2; mi++)
#pragma unroll
        for (int nb = 0; nb < 6; nb++) acc[mi][nb] = (v4f){0.f, 0.f, 0.f, 0.f};

    for (int k0 = 0; k0 < K; k0 += 32) {
#pragma unroll
        for (int t = 0; t < 2; t++) {
            int ch = tid + t * 256;
            int r = ch >> 2, kq = ch & 3;
            int rg = rb + r;
            uint4 v = make_uint4(0u, 0u, 0u, 0u);
            if (rg < N) v = *reinterpret_cast<const uint4*>(&Xb[(long)rg * K + k0 + kq * 8]);
            uint2* d = reinterpret_cast<uint2*>(&XT_l[r * 40 + kq * 8]);
            d[0] = make_uint2(v.x, v.y);
            d[1] = make_uint2(v.z, v.w);
        }
#pragma unroll
        for (int t = 0; t < 2; t++) {
            int ch = tid + t * 256;
            if (ch < 384) {
                int wr = ch >> 2, kq = ch & 3;
                uint4 v = *reinterpret_cast<const uint4*>(&WT[(long)(c0 + wr) * K + k0 + kq * 8]);
                uint2* d = reinterpret_cast<uint2*>(&WT_l[wr * 40 + kq * 8]);
                d[0] = make_uint2(v.x, v.y);
                d[1] = make_uint2(v.z, v.w);
            }
        }
        __syncthreads();
        v8s af[2], bf[6];
        af[0] = ld_frag(&XT_l[(mw + m) * 40 + quad * 8]);
        af[1] = ld_frag(&XT_l[(mw + 16 + m) * 40 + quad * 8]);
#pragma unroll
        for (int nb = 0; nb < 6; nb++)
            bf[nb] = ld_frag(&WT_l[(nb * 16 + m) * 40 + quad * 8]);
#pragma unroll
        for (int mi = 0; mi < 2; mi++)
#pragma unroll
            for (int nb = 0; nb < 6; nb++)
                acc[mi][nb] = __builtin_amdgcn_mfma_f32_16x16x32_bf16(af[mi], bf[nb], acc[mi][nb], 0, 0, 0);
        __syncthreads();
    }

#pragma unroll
    for (int mi = 0; mi < 2; mi++)
#pragma unroll
        for (int r = 0; r < 4; r++) {
            int R = rb + mw + mi * 16 + quad * 4 + r;
            if (R < N) {
#pragma unroll
                for (int nb = 0; nb < 6; nb++)
                    Hb[(long)R * NCT + c0 + nb * 16 + m] = (ushort)bf16r(acc[mi][nb][r]);
            }
        }

    // ---- fused attention dots from fp32 accumulator ----
    float aS[6], aD[6];
    int h0 = c0 / DD;
#pragma unroll
    for (int nb = 0; nb < 6; nb++) {
        int cb = nb * 16 + m;
        int hl = cb / DD;
        int cih = cb - hl * DD;
        aS[nb] = att_s[(h0 + hl) * DD + cih];
        aD[nb] = att_d[(h0 + hl) * DD + cih];
    }
#pragma unroll
    for (int mi = 0; mi < 2; mi++)
#pragma unroll
        for (int r = 0; r < 4; r++) {
            float ps0 = 0.f, ps1 = 0.f, pd0 = 0.f, pd1 = 0.f;
#pragma unroll
            for (int nb = 0; nb < 3; nb++) {
                ps0 = fmaf(acc[mi][nb][r], aS[nb], ps0);
                pd0 = fmaf(acc[mi][nb][r], aD[nb], pd0);
            }
#pragma unroll
            for (int nb = 3; nb < 6; nb++) {
                ps1 = fmaf(acc[mi][nb][r], aS[nb], ps1);
                pd1 = fmaf(acc[mi][nb][r], aD[nb], pd1);
            }
#pragma unroll
            for (int d = 1; d < 16; d <<= 1) {
                ps0 += __shfl_xor(ps0, d); ps1 += __shfl_xor(ps1, d);
                pd0 += __shfl_xor(pd0, d); pd1 += __shfl_xor(pd1, d);
            }
            int R = rb + mw + mi * 16 + quad * 4 + r;
            if (m == 0 && R < N) {
                asrc[R * HEADS + h0]     = ps0;
                asrc[R * HEADS + h0 + 1] = ps1;
                adst[R * HEADS + h0]     = pd0;
                adst[R * HEADS + h0 + 1] = pd1;
            }
        }
}

// ---------------- dst-centric fused softmax + aggregate + bias + relu ----------------
// R10: edge-parallel lane split. Wave processes EPW edges at once; each edge is
// handled by 64/EPW lanes owning 3 uints (6 bf16 channels) via one dwordx3.
// All 64 lanes active; wave-instructions per edge cut ~EPWx vs R8. Cross-edge
// combine = shfl_xor at the end. Pads (deg -> mult of 2*EPW) hit L1-hot row 0
// with w=0. wlds head-stride 65 keeps weight reads conflict-free.
template<int OUT, int HEADS, int EPW, bool OBF16>
__global__ void agg_kernel(const unsigned int* __restrict__ Hb,
                           const float* __restrict__ asrc, const float* __restrict__ adst,
                           const int* __restrict__ adj, const int* __restrict__ cnt,
                           const float* __restrict__ bias,
                           unsigned int* __restrict__ Ob, float* __restrict__ Of, int N) {
    constexpr int LPE = 64 / EPW;              // lanes per edge (32 or 16)
    constexpr int ROWU = OUT / 2;              // uints per row (96 or 48); LPE*3 == ROWU
    __shared__ float wlds[4][HEADS][CAP + 1];  // head stride 65 -> distinct banks
    __shared__ float dlds[4][HEADS];
    __shared__ int   slds[4][CAP];
    int wv = threadIdx.x >> 6;
    int lane = threadIdx.x & 63;
    int esub = lane / LPE;                     // which edge of the EPW group
    int lp   = lane % LPE;                     // lane-within-edge: 3 uints / 6 channels
    int n = blockIdx.x * 4 + wv;
    bool valid = (n < N);
    int nn = valid ? n : 0;
    int deg_raw = cnt[nn];                     // issue cnt+adj concurrently
    int araw = adj[nn * CAP + lane];
    int deg = min(deg_raw, CAP);
    int s = (lane < deg) ? araw : 0;
    slds[wv][lane] = s;

    float av[HEADS], dvv[HEADS];
    if constexpr (HEADS == 4) {
        float4 t = *reinterpret_cast<const float4*>(&asrc[s * 4]);
        av[0] = t.x; av[1] = t.y; av[2] = t.z; av[3] = t.w;
        float4 u = *reinterpret_cast<const float4*>(&adst[nn * 4]);
        dvv[0] = u.x; dvv[1] = u.y; dvv[2] = u.z; dvv[3] = u.w;
    } else {
        float2 t = *reinterpret_cast<const float2*>(&asrc[s * 2]);
        av[0] = t.x; av[1] = t.y;
        float2 u = *reinterpret_cast<const float2*>(&adst[nn * 2]);
        dvv[0] = u.x; dvv[1] = u.y;
    }
    float w[HEADS];
#pragma unroll
    for (int h = 0; h < HEADS; h++) {
        float e = av[h] + dvv[h];
        e = (e < 0.f) ? 0.2f * e : e;               // leaky_relu, slope 0.2
        w[h] = (lane < deg) ? __expf(e) : 0.f;      // max-shift dropped: scale-invariant
        wlds[wv][h][lane] = w[h];
    }
#pragma unroll
    for (int h = 0; h < HEADS; h++) {               // den = wave-sum of weights
        float dsum = w[h];
#pragma unroll
        for (int off = 1; off < 64; off <<= 1) dsum += __shfl_xor(dsum, off);
        if (lane == 0) dlds[wv][h] = dsum;
    }
    __syncthreads();

    int c = lp * 6;                                 // 6 channels, never straddles a head
    int head = c / DD;
    const float* wrow = &wlds[wv][head][0];
    v2f a0 = (v2f){0.f, 0.f}, a1 = (v2f){0.f, 0.f}, a2 = (v2f){0.f, 0.f};

    for (int base = 0; base < deg; base += 2 * EPW) {   // 2-unroll: 2 loads in flight/lane
        int e0 = base + esub, e1 = base + EPW + esub;
        int s0 = slds[wv][e0], s1 = slds[wv][e1];
        uint3 h0 = *reinterpret_cast<const uint3*>(&Hb[(long)s0 * ROWU + lp * 3]);
        uint3 h1 = *reinterpret_cast<const uint3*>(&Hb[(long)s1 * ROWU + lp * 3]);
        float w0 = wrow[e0], w1 = wrow[e1];
        v2f p;
        p.x = __uint_as_float(h0.x << 16); p.y = __uint_as_float(h0.x & 0xFFFF0000u);
        a0 += w0 * p;
        p.x = __uint_as_float(h0.y << 16); p.y = __uint_as_float(h0.y & 0xFFFF0000u);
        a1 += w0 * p;
        p.x = __uint_as_float(h0.z << 16); p.y = __uint_as_float(h0.z & 0xFFFF0000u);
        a2 += w0 * p;
        p.x = __uint_as_float(h1.x << 16); p.y = __uint_as_float(h1.x & 0xFFFF0000u);
        a0 += w1 * p;
        p.x = __uint_as_float(h1.y << 16); p.y = __uint_as_float(h1.y & 0xFFFF0000u);
        a1 += w1 * p;
        p.x = __uint_as_float(h1.z << 16); p.y = __uint_as_float(h1.z & 0xFFFF0000u);
        a2 += w1 * p;
    }

    // combine the EPW edge subgroups (lanes differing only in esub share channels)
#pragma unroll
    for (int off = LPE; off < 64; off <<= 1) {
        a0.x += __shfl_xor(a0.x, off); a0.y += __shfl_xor(a0.y, off);
        a1.x += __shfl_xor(a1.x, off); a1.y += __shfl_xor(a1.y, off);
        a2.x += __shfl_xor(a2.x, off); a2.y += __shfl_xor(a2.y, off);
    }

    if (valid && esub == 0) {
        float invd = 1.f / (dlds[wv][head] + 1e-16f);
        float o[6];
        o[0] = fmaxf(fmaf(a0.x, invd, bias[c + 0]), 0.f);
        o[1] = fmaxf(fmaf(a0.y, invd, bias[c + 1]), 0.f);
        o[2] = fmaxf(fmaf(a1.x, invd, bias[c + 2]), 0.f);
        o[3] = fmaxf(fmaf(a1.y, invd, bias[c + 3]), 0.f);
        o[4] = fmaxf(fmaf(a2.x, invd, bias[c + 4]), 0.f);
        o[5] = fmaxf(fmaf(a2.y, invd, bias[c + 5]), 0.f);
        if (OBF16) {
            uint3 pk;
            pk.x = bf16r(o[0]) | (bf16r(o[1]) << 16);
            pk.y = bf16r(o[2]) | (bf16r(o[3]) << 16);
            pk.z = bf16r(o[4]) | (bf16r(o[5]) << 16);
            *reinterpret_cast<uint3*>(&Ob[(long)n * ROWU + lp * 3]) = pk;
        } else {
            float* dst = &Of[(long)n * OUT + c];
            *reinterpret_cast<float2*>(dst)     = make_float2(o[0], o[1]);
            *reinterpret_cast<float2*>(dst + 2) = make_float2(o[2], o[3]);
            *reinterpret_cast<float2*>(dst + 4) = make_float2(o[4], o[5]);
        }
    }
}

// ---------------- mean-pool: 128-thread groups, 64-node chunks, 4x-unrolled ----------------
__global__ void pool_kernel(const float* __restrict__ O, const int* __restrict__ batch,
                            float* __restrict__ sums, float* __restrict__ counts, int N) {
    int grp = threadIdx.x >> 7;                 // 4 groups of 128 per block
    int c = threadIdx.x & 127;                  // channel lane; active if < 96
    int n0 = (blockIdx.x * 4 + grp) * 64;
    if (n0 >= N) return;
    int nend = min(N, n0 + 64);
    bool act = (c < 96);
    float acc = 0.f; int cl = 0;
    int cur = batch[n0];
    int n = n0;
    for (; n + 4 <= nend; n += 4) {
        int g0 = batch[n], g1 = batch[n + 1], g2 = batch[n + 2], g3 = batch[n + 3];
        float v0 = 0.f, v1 = 0.f, v2 = 0.f, v3 = 0.f;
        if (act) {
            v0 = O[(long)n * 96 + c];       v1 = O[(long)(n + 1) * 96 + c];
            v2 = O[(long)(n + 2) * 96 + c]; v3 = O[(long)(n + 3) * 96 + c];
        }
#define POOL_STEP(g, v)                                                        \
        if ((g) != cur) {                                                      \
            if (act) atomicAdd(&sums[cur * 96 + c], acc);                      \
            if (c == 96) atomicAdd(&counts[cur], (float)cl);                   \
            acc = 0.f; cl = 0; cur = (g);                                      \
        }                                                                      \
        acc += (v); cl++;
        POOL_STEP(g0, v0) POOL_STEP(g1, v1) POOL_STEP(g2, v2) POOL_STEP(g3, v3)
    }
    for (; n < nend; n++) {
        int g = batch[n];
        float v = act ? O[(long)n * 96 + c] : 0.f;
        POOL_STEP(g, v)
    }
#undef POOL_STEP
    if (act) atomicAdd(&sums[cur * 96 + c], acc);
    if (c == 96) atomicAdd(&counts[cur], (float)cl);
}

// ---------------- FC head: one block per graph ----------------
__global__ void fc_kernel(const float* __restrict__ sums, const float* __restrict__ counts,
                          const float* __restrict__ W1, const float* __restrict__ b1,
                          const float* __restrict__ W2, const float* __restrict__ b2,
                          float* __restrict__ out) {
    __shared__ float p[96];
    __shared__ float h1[192];
    int g = blockIdx.x, tid = threadIdx.x;     // 192 threads
    if (tid < 96) p[tid] = sums[g * 96 + tid] / fmaxf(counts[g], 1.0f);
    __syncthreads();
    float s = b1[tid];
    for (int c = 0; c < 96; c++) s = fmaf(p[c], W1[c * 192 + tid], s);
    h1[tid] = fmaxf(s, 0.f);
    __syncthreads();
    if (tid < 96) {
        float s2 = b2[tid];
        for (int j = 0; j < 192; j++) s2 = fmaf(h1[j], W2[j * 96 + tid], s2);
        out[g * 96 + tid] = s2;
    }
}

extern "C" void kernel_launch(void* const* d_in, const int* in_sizes, int n_in,
                              void* d_out, int out_size, void* d_ws, size_t ws_size,
                              hipStream_t stream) {
    const float* x     = (const float*)d_in[0];
    const int*   ei    = (const int*)d_in[1];
    const int*   batch = (const int*)d_in[2];
    const float* W0  = (const float*)d_in[3];
    const float* as0 = (const float*)d_in[4];
    const float* ad0 = (const float*)d_in[5];
    const float* b0  = (const float*)d_in[6];
    const float* W1  = (const float*)d_in[7];
    const float* as1 = (const float*)d_in[8];
    const float* ad1 = (const float*)d_in[9];
    const float* b1  = (const float*)d_in[10];
    const float* W2  = (const float*)d_in[11];
    const float* as2 = (const float*)d_in[12];
    const float* ad2 = (const float*)d_in[13];
    const float* b2  = (const float*)d_in[14];
    const float* fcW1 = (const float*)d_in[15];
    const float* fcb1 = (const float*)d_in[16];
    const float* fcW2 = (const float*)d_in[17];
    const float* fcb2 = (const float*)d_in[18];

    const int N = in_sizes[0] / 128;
    const int E = in_sizes[1] / 2;

    char* ws = (char*)d_ws;
    unsigned int* Xb   = (unsigned int*)ws;                          // N*128 bf16 = N*256 B
    unsigned int* Hb   = (unsigned int*)(ws + (size_t)N * 256);      // N*192 bf16 = N*384 B
    unsigned int* Ob   = (unsigned int*)(ws + (size_t)N * 640);      // N*192 bf16 = N*384 B
    float*        Obuf = (float*)(ws + (size_t)N * 1024);            // N*96 f32  = N*384 B
    float*        ASRC = (float*)(ws + (size_t)N * 1408);            // N*4 f
    float*        ADST = (float*)(ws + (size_t)N * 1424);            // N*4 f
    int*          ADJ  = (int*)(ws + (size_t)N * 1440);              // N*CAP i  = N*256 B
    int*          CNT  = (int*)(ws + (size_t)N * 1696);              // N i
    float*        SUMS = (float*)(ws + (size_t)N * 1700);            // 64*96 f
    float*        COUNTS = SUMS + 64 * 96;                           // 64 f
    ushort*       WT0  = (ushort*)(COUNTS + 64);                     // 192*128 bf16
    ushort*       WT1  = WT0 + 192 * 128;                            // 96*192 bf16
    ushort*       WT2  = WT1 + 96 * 192;                             // 96*96 bf16

    hipMemsetAsync(CNT, 0, (size_t)N * 4 + (64 * 96 + 64) * 4, stream);

    int Et = E + N;
    build_adj_kernel<<<(Et + 255) / 256, 256, 0, stream>>>(ei, E, N, CNT, ADJ);

    long n2 = (long)N * 64;
    cast_x_kernel<<<(int)((n2 + 255) / 256), 256, 0, stream>>>(x, Xb, n2);
    convw_kernel<<<(128 * 192 + 255) / 256, 256, 0, stream>>>(W0, WT0, 128, 192);
    convw_kernel<<<(192 * 96 + 255) / 256, 256, 0, stream>>>(W1, WT1, 192, 96);
    convw_kernel<<<(96 * 96 + 255) / 256, 256, 0, stream>>>(W2, WT2, 96, 96);

    int gb = (N + 127) / 128;

    // layer 0: 128 -> 4x48  (EPW=2: 2 edges x 32 lanes x dwordx3)
    gemm_mfma<128, 192, 4><<<dim3(gb, 2), 256, 0, stream>>>((const ushort*)Xb, WT0, as0, ad0,
                                                            (ushort*)Hb, ASRC, ADST, N);
    agg_kernel<192, 4, 2, true><<<(N + 3) / 4, 256, 0, stream>>>(Hb, ASRC, ADST, ADJ, CNT, b0, Ob, nullptr, N);

    // layer 1: 192 -> 2x48  (EPW=4: 4 edges x 16 lanes x dwordx3)
    gemm_mfma<192, 96, 2><<<dim3(gb, 1), 256, 0, stream>>>((const ushort*)Ob, WT1, as1, ad1,
                                                           (ushort*)Hb, ASRC, ADST, N);
    agg_kernel<96, 2, 4, true><<<(N + 3) / 4, 256, 0, stream>>>(Hb, ASRC, ADST, ADJ, CNT, b1, Ob, nullptr, N);

    // layer 2: 96 -> 2x48
    gemm_mfma<96, 96, 2><<<dim3(gb, 1), 256, 0, stream>>>((const ushort*)Ob, WT2, as2, ad2,
                                                          (ushort*)Hb, ASRC, ADST, N);
    agg_kernel<96, 2, 4, false><<<(N + 3) / 4, 256, 0, stream>>>(Hb, ASRC, ADST, ADJ, CNT, b2, nullptr, Obuf, N);

    // pooling + FC head
    pool_kernel<<<(N / 256) + 1, 512, 0, stream>>>(Obuf, batch, SUMS, COUNTS, N);
    fc_kernel<<<64, 192, 0, stream>>>(SUMS, COUNTS, fcW1, fcb1, fcW2, fcb2, (float*)d_out);
}